// Round 1
// baseline (92.378 us; speedup 1.0000x reference)
//
#include <hip/hip_runtime.h>
#include <hip/hip_bf16.h>

// Problem: MoChA monotonic+chunkwise attention.
// B=32, S=2048, D=512, A=128. All inputs fp32, outputs fp32:
// d_out = [context (32*512) | alpha (32*2048) | beta (32*2048)]

#define S_LEN 2048
#define D_DIM 512
#define A_DIM 128
#define NCOLS 256            // mono(128) + chunk(128) concatenated
#define NROWS 65536          // B*S

typedef __attribute__((ext_vector_type(8))) short bf16x8;
typedef __attribute__((ext_vector_type(4))) float f32x4;

__device__ __forceinline__ unsigned short f2bf(float f) {
    unsigned int u = __float_as_uint(f);
    unsigned int r = (u + 0x7FFFu + ((u >> 16) & 1u)) >> 16;  // RNE
    return (unsigned short)r;
}

__device__ __forceinline__ float fast_tanh(float x) {
    float ax = fabsf(x);
    float z = __expf(-2.f * ax);
    float t = (1.f - z) / (1.f + z);
    return x >= 0.f ? t : -t;
}

// ---------------- prep kernels ----------------

__global__ void prep_weff(const float* __restrict__ mvv, const float* __restrict__ mvg,
                          const float* __restrict__ cvv, const float* __restrict__ cvg,
                          float* __restrict__ weff) {
    __shared__ float red[256];
    int t = threadIdx.x;
    float v = (t < 128) ? mvv[t] : cvv[t - 128];
    red[t] = v * v;
    __syncthreads();
    for (int off = 64; off > 0; off >>= 1) {
        if ((t & 127) < off) red[t] += red[t + off];
        __syncthreads();
    }
    float nrm = sqrtf((t < 128) ? red[0] : red[128]);
    float g = (t < 128) ? mvg[0] : cvg[0];
    weff[t] = g * v / nrm;
}

__global__ void prep_wcat(const float* __restrict__ mW, const float* __restrict__ cW,
                          unsigned short* __restrict__ Wb) {
    int i = blockIdx.x * 256 + threadIdx.x;  // grid 512 * 256 == 131072 exactly
    int a = i >> 9, k = i & 511;
    float v = (a < 128) ? mW[a * 512 + k] : cW[(a - 128) * 512 + k];
    Wb[i] = f2bf(v);
}

__global__ void prep_bias(const float* __restrict__ dec, const float* __restrict__ mV,
                          const float* __restrict__ cV, const float* __restrict__ mb,
                          const float* __restrict__ cb, float* __restrict__ bias) {
    __shared__ float sdec[512];
    int b = blockIdx.x, t = threadIdx.x;
    sdec[t] = dec[b * 512 + t];
    sdec[t + 256] = dec[b * 512 + 256 + t];
    __syncthreads();
    int a = t & 127;
    const float* Vp = ((t < 128) ? mV : cV) + a * 512;
    float acc = 0.f;
#pragma unroll 8
    for (int k = 0; k < 512; k += 4) {
        float4 w = *(const float4*)(Vp + k);
        acc += sdec[k] * w.x + sdec[k + 1] * w.y + sdec[k + 2] * w.z + sdec[k + 3] * w.w;
    }
    bias[b * 256 + t] = acc + ((t < 128) ? mb[a] : cb[a]);
}

// ---------------- main energy GEMM (bf16 MFMA) ----------------
// tile: 128 rows x 256 cols, K chunks of 32. 8 waves: wr in {0,1}, wc in {0..3}.
// Each wave: 64 rows x 64 cols = 4x4 frags of 16x16, K=32 per mfma.

__launch_bounds__(512, 2)
__global__ void gemm_energy(const float* __restrict__ enc,
                            const unsigned short* __restrict__ Wb,
                            const float* __restrict__ bias,
                            const float* __restrict__ weff,
                            const float* __restrict__ mvb, const float* __restrict__ mr,
                            const float* __restrict__ cvb, const float* __restrict__ cr,
                            float* __restrict__ mono_e, float* __restrict__ uval) {
    __shared__ unsigned short sA[128 * 40];  // 32 k + 8 pad per row
    __shared__ unsigned short sB[256 * 40];
    __shared__ float sBias[256];
    __shared__ float sWeff[256];
    __shared__ float sPart[4][128];

    int tid = threadIdx.x;
    int br = blockIdx.x;
    int row0 = br * 128;
    int b = row0 >> 11;  // S=2048, 128-row tiles never cross b
    if (tid < 256) { sBias[tid] = bias[b * 256 + tid]; sWeff[tid] = weff[tid]; }

    int lane = tid & 63;
    int w = tid >> 6;
    int wr = w >> 2, wc = w & 3;
    int fr = lane & 15, fg = lane >> 4;

    f32x4 acc[4][4];
#pragma unroll
    for (int i = 0; i < 4; i++)
#pragma unroll
        for (int j = 0; j < 4; j++) acc[i][j] = (f32x4){0.f, 0.f, 0.f, 0.f};

    int arow = tid >> 2, aq = tid & 3;     // A stage: 128 rows, 2x float4 each
    int bcol = tid >> 1, bg = tid & 1;     // B stage: 256 cols, 16 bf16 each
    const float* aptr = enc + (size_t)(row0 + arow) * 512;
    const unsigned short* bptr = Wb + bcol * 512 + bg * 16;

    for (int k0 = 0; k0 < 512; k0 += 32) {
        float4 va = *(const float4*)(aptr + k0 + aq * 4);
        float4 vb = *(const float4*)(aptr + k0 + aq * 4 + 16);
        ushort4 pa = make_ushort4(f2bf(va.x), f2bf(va.y), f2bf(va.z), f2bf(va.w));
        ushort4 pb = make_ushort4(f2bf(vb.x), f2bf(vb.y), f2bf(vb.z), f2bf(vb.w));
        *(ushort4*)&sA[arow * 40 + aq * 4] = pa;
        *(ushort4*)&sA[arow * 40 + aq * 4 + 16] = pb;
        uint4 w0 = *(const uint4*)(bptr + k0);
        uint4 w1 = *(const uint4*)(bptr + k0 + 8);
        *(uint4*)&sB[bcol * 40 + bg * 16] = w0;
        *(uint4*)&sB[bcol * 40 + bg * 16 + 8] = w1;
        __syncthreads();

        bf16x8 af[4], bfr[4];
#pragma unroll
        for (int rt = 0; rt < 4; rt++)
            af[rt] = *(const bf16x8*)&sA[(wr * 64 + rt * 16 + fr) * 40 + fg * 8];
#pragma unroll
        for (int ct = 0; ct < 4; ct++)
            bfr[ct] = *(const bf16x8*)&sB[(wc * 64 + ct * 16 + fr) * 40 + fg * 8];
#pragma unroll
        for (int rt = 0; rt < 4; rt++)
#pragma unroll
            for (int ct = 0; ct < 4; ct++)
                acc[rt][ct] = __builtin_amdgcn_mfma_f32_16x16x32_bf16(af[rt], bfr[ct], acc[rt][ct], 0, 0, 0);
        __syncthreads();
    }

    // epilogue: tanh + weighted col-reduction
    float psum[4][4];
#pragma unroll
    for (int i = 0; i < 4; i++)
#pragma unroll
        for (int j = 0; j < 4; j++) psum[i][j] = 0.f;
#pragma unroll
    for (int ct = 0; ct < 4; ct++) {
        int colg = wc * 64 + ct * 16 + fr;
        float wv = sWeff[colg], bv = sBias[colg];
#pragma unroll
        for (int rt = 0; rt < 4; rt++)
#pragma unroll
            for (int i = 0; i < 4; i++)
                psum[rt][i] += fast_tanh(acc[rt][ct][i] + bv) * wv;
    }
#pragma unroll
    for (int off = 1; off < 16; off <<= 1)
#pragma unroll
        for (int rt = 0; rt < 4; rt++)
#pragma unroll
            for (int i = 0; i < 4; i++)
                psum[rt][i] += __shfl_xor(psum[rt][i], off, 64);
    if (fr == 0) {
#pragma unroll
        for (int rt = 0; rt < 4; rt++)
#pragma unroll
            for (int i = 0; i < 4; i++)
                sPart[wc][wr * 64 + rt * 16 + fg * 4 + i] = psum[rt][i];
    }
    __syncthreads();
    if (tid < 256) {
        int rl = tid & 127, half = tid >> 7;
        float v = sPart[half * 2][rl] + sPart[half * 2 + 1][rl];
        int rg = row0 + rl;
        if (half == 0) mono_e[rg] = v + mvb[0] + mr[0];
        else           uval[rg]   = v + cvb[0] + cr[0];
    }
}

// ---------------- per-b scans + moving sums ----------------

__global__ void scan_kernel(const float* __restrict__ mono_e, const float* __restrict__ uval,
                            const float* __restrict__ pa, const float* __restrict__ noise,
                            float* __restrict__ alpha_out, float* __restrict__ beta_out) {
    __shared__ float sEU[2048];
    __shared__ float sR[2048];
    __shared__ float sred[256];
    __shared__ float sScan[256];
    int b = blockIdx.x, t = threadIdx.x;
    const int base = b * 2048;
    int s0 = t * 8;

    float u8[8], me8[8], n8[8], pa8[8];
    *(float4*)&u8[0]  = *(const float4*)(uval + base + s0);
    *(float4*)&u8[4]  = *(const float4*)(uval + base + s0 + 4);
    *(float4*)&me8[0] = *(const float4*)(mono_e + base + s0);
    *(float4*)&me8[4] = *(const float4*)(mono_e + base + s0 + 4);
    *(float4*)&n8[0]  = *(const float4*)(noise + base + s0);
    *(float4*)&n8[4]  = *(const float4*)(noise + base + s0 + 4);
    *(float4*)&pa8[0] = *(const float4*)(pa + base + s0);
    *(float4*)&pa8[4] = *(const float4*)(pa + base + s0 + 4);

    float lmax = u8[0];
#pragma unroll
    for (int j = 1; j < 8; j++) lmax = fmaxf(lmax, u8[j]);
    sred[t] = lmax;
    __syncthreads();
    for (int off = 128; off > 0; off >>= 1) {
        if (t < off) sred[t] = fmaxf(sred[t], sred[t + off]);
        __syncthreads();
    }
    float umax = sred[0];

    float eu8[8];
#pragma unroll
    for (int j = 0; j < 8; j++) {
        eu8[j] = fmaxf(expf(u8[j] - umax), 1e-5f);
        sEU[s0 + j] = eu8[j];
    }

    // p_select, log(1-p), thread-local inclusive cumsum
    float p8[8], c8[8];
    float run = 0.f;
#pragma unroll
    for (int j = 0; j < 8; j++) {
        float x = me8[j] + n8[j];
        float p = 1.f / (1.f + expf(-x));
        p8[j] = p;
        float om = fminf(fmaxf(1.f - p, 1e-10f), 1.f);
        run += logf(om);
        c8[j] = run;
    }
    sScan[t] = run;
    __syncthreads();
    for (int off = 1; off < 256; off <<= 1) {
        float cur = sScan[t];
        float add = (t >= off) ? sScan[t - off] : 0.f;
        __syncthreads();
        sScan[t] = cur + add;
        __syncthreads();
    }
    float excl = sScan[t] - run;

    // cumprod, pa/cumprod cumsum
    float cp8[8], d8[8];
    float run2 = 0.f;
#pragma unroll
    for (int j = 0; j < 8; j++) {
        float S1 = excl + c8[j];
        cp8[j] = expf(S1);
        run2 += pa8[j] / cp8[j];
        d8[j] = run2;
    }
    __syncthreads();
    sScan[t] = run2;
    __syncthreads();
    for (int off = 1; off < 256; off <<= 1) {
        float cur = sScan[t];
        float add = (t >= off) ? sScan[t - off] : 0.f;
        __syncthreads();
        sScan[t] = cur + add;
        __syncthreads();
    }
    float excl2 = sScan[t] - run2;

    float al8[8];
#pragma unroll
    for (int j = 0; j < 8; j++) {
        float T = excl2 + d8[j];
        al8[j] = p8[j] * cp8[j] * T;
    }
    *(float4*)(alpha_out + base + s0)     = *(float4*)&al8[0];
    *(float4*)(alpha_out + base + s0 + 4) = *(float4*)&al8[4];

    // r = alpha / denom  (denom: window [s-7, s] of exp_u, zero-padded)
#pragma unroll
    for (int j = 0; j < 8; j++) {
        int s = s0 + j;
        float dsum = 0.f;
        for (int k = s - 7; k <= s; k++)
            if (k >= 0) dsum += sEU[k];
        sR[s] = al8[j] / dsum;
    }
    __syncthreads();

    float bt8[8];
#pragma unroll
    for (int j = 0; j < 8; j++) {
        int s = s0 + j;
        float msum = 0.f;
        for (int k = s; k <= s + 7; k++)
            if (k < 2048) msum += sR[k];
        bt8[j] = eu8[j] * msum;
    }
    *(float4*)(beta_out + base + s0)     = *(float4*)&bt8[0];
    *(float4*)(beta_out + base + s0 + 4) = *(float4*)&bt8[4];
}

// ---------------- context = enc^T beta ----------------

__global__ void ctx_partial(const float* __restrict__ enc, const float* __restrict__ beta,
                            float* __restrict__ parts) {
    int b = blockIdx.y;
    int sc = blockIdx.x >> 1, dt = blockIdx.x & 1;
    __shared__ float sb[128];
    int t = threadIdx.x;
    if (t < 128) sb[t] = beta[b * 2048 + sc * 128 + t];
    __syncthreads();
    int d = dt * 256 + t;
    const float* ep = enc + ((size_t)(b * 2048 + sc * 128)) * 512 + d;
    float acc = 0.f;
#pragma unroll 8
    for (int i = 0; i < 128; i++) acc += sb[i] * ep[(size_t)i * 512];
    parts[(sc * 32 + b) * 512 + d] = acc;
}

__global__ void ctx_reduce(const float* __restrict__ parts, float* __restrict__ ctx) {
    int i = blockIdx.x * 256 + threadIdx.x;  // 16384 total
    float s = 0.f;
#pragma unroll
    for (int j = 0; j < 16; j++) s += parts[i + j * 16384];
    ctx[i] = s;
}

// ---------------- launch ----------------

extern "C" void kernel_launch(void* const* d_in, const int* in_sizes, int n_in,
                              void* d_out, int out_size, void* d_ws, size_t ws_size,
                              hipStream_t stream) {
    const float* enc   = (const float*)d_in[0];
    const float* dec   = (const float*)d_in[1];
    const float* pa    = (const float*)d_in[2];
    const float* noise = (const float*)d_in[3];
    const float* mW  = (const float*)d_in[4];
    const float* mV  = (const float*)d_in[5];
    const float* mb  = (const float*)d_in[6];
    const float* mvv = (const float*)d_in[7];
    const float* mvg = (const float*)d_in[8];
    const float* mvb = (const float*)d_in[9];
    const float* mr  = (const float*)d_in[10];
    const float* cW  = (const float*)d_in[11];
    const float* cV  = (const float*)d_in[12];
    const float* cb  = (const float*)d_in[13];
    const float* cvv = (const float*)d_in[14];
    const float* cvg = (const float*)d_in[15];
    const float* cvb = (const float*)d_in[16];
    const float* cr  = (const float*)d_in[17];

    char* w = (char*)d_ws;
    unsigned short* Wb = (unsigned short*)w;              // 256*512*2   = 262144
    float* weff  = (float*)(w + 262144);                  // 256*4       = 1024
    float* bias  = (float*)(w + 263168);                  // 32*256*4    = 32768
    float* mono  = (float*)(w + 295936);                  // 65536*4     = 262144
    float* uu    = (float*)(w + 558080);                  // 65536*4     = 262144
    float* parts = (float*)(w + 820224);                  // 16*32*512*4 = 1048576

    float* ctx   = (float*)d_out;
    float* alpha = ctx + 16384;
    float* beta  = ctx + 81920;

    hipLaunchKernelGGL(prep_weff, dim3(1), dim3(256), 0, stream, mvv, mvg, cvv, cvg, weff);
    hipLaunchKernelGGL(prep_wcat, dim3(512), dim3(256), 0, stream, mW, cW, Wb);
    hipLaunchKernelGGL(prep_bias, dim3(32), dim3(256), 0, stream, dec, mV, cV, mb, cb, bias);
    hipLaunchKernelGGL(gemm_energy, dim3(512), dim3(512), 0, stream,
                       enc, Wb, bias, weff, mvb, mr, cvb, cr, mono, uu);
    hipLaunchKernelGGL(scan_kernel, dim3(32), dim3(256), 0, stream, mono, uu, pa, noise, alpha, beta);
    hipLaunchKernelGGL(ctx_partial, dim3(32, 32), dim3(256), 0, stream, enc, beta, parts);
    hipLaunchKernelGGL(ctx_reduce, dim3(64), dim3(256), 0, stream, parts, ctx);
}